// Round 3
// baseline (404.150 us; speedup 1.0000x reference)
//
#include <hip/hip_runtime.h>

// Caps_Layer round 3: two-kernel split.
// K1: streaming GEMM x[N,120]*W[120,25] -> u_hat[N,25] (d_ws). Contiguous
//     64-row tiles, double-buffered LDS, wave roles = (k-half, j-half) so W
//     loads are scalar (s_load) amortized over 64 rows; coalesced f4 stores.
// K2: routing per batch element; u_hat chunk staged coalesced into LDS
//     (stride 25 is odd -> conflict-free row reads), routing in registers.

#define NCAP 5
#define DCAP 5
#define NOUT 25
#define DIN 120
#define SEQ 512
#define ROUTINGS 4

#define TROWS 64
#define TILES 8          // 512 rows per block
#define XS   121         // LDS row stride (odd -> conflict-free b32 reads)
#define NF4  1920        // TROWS*DIN/4 float4 per tile

__global__ __launch_bounds__(256) void gemm_kernel(
    const float* __restrict__ x,   // [nrows, 120]
    const float* __restrict__ W,   // [120, 25]
    float* __restrict__ u)         // [nrows, 25]
{
    __shared__ __align__(16) float xs[2][TROWS * XS];   // 2 x 30,976 B
    __shared__ __align__(16) float us[2][TROWS * NOUT]; // 2 x  6,400 B

    const int t    = threadIdx.x;
    const int lane = t & 63;
    const int wv   = __builtin_amdgcn_readfirstlane(t >> 6);
    const int jh   = wv & 1;        // j-half: 0 -> j 0..11, 1 -> j 12..24
    const int kh   = wv >> 1;       // k-half: 0 -> k 0..59, 1 -> k 60..119
    const int j0   = jh * 12;
    const int jcnt = jh ? 13 : 12;

    const long rowsBase = (long)blockIdx.x * (TILES * TROWS);

    // prologue: stage tile 0 (contiguous 30.7 KB global chunk)
    {
        const float4* src = (const float4*)(x + rowsBase * DIN);
#pragma unroll
        for (int i = 0; i < 8; ++i) {
            int f = t + 256 * i;
            if (f < NF4) {
                float4 v = src[f];
                int r = f / 30, q = f - 30 * r;
                float* d = &xs[0][r * XS + 4 * q];
                d[0] = v.x; d[1] = v.y; d[2] = v.z; d[3] = v.w;
            }
        }
    }
    __syncthreads();

    for (int tile = 0; tile < TILES; ++tile) {
        const int cur  = tile & 1;
        const int nxt  = cur ^ 1;
        const bool more = (tile + 1 < TILES);

        // issue next tile's loads; they fly during compute (acc is only 13 regs)
        float4 L[8];
        if (more) {
            const float4* src =
                (const float4*)(x + (rowsBase + (long)(tile + 1) * TROWS) * DIN);
#pragma unroll
            for (int i = 0; i < 8; ++i) {
                int f = t + 256 * i;
                L[i] = (f < NF4) ? src[f] : make_float4(0.f, 0.f, 0.f, 0.f);
            }
        }

        // compute: lane = row, this wave's (k-half, j-half)
        float acc[13];
#pragma unroll
        for (int j = 0; j < 13; ++j) acc[j] = 0.f;
        const float* xr = &xs[cur][lane * XS + kh * 60];
        const float* wk = W + (kh * 60) * NOUT + j0;   // wave-uniform -> s_load
#pragma unroll 4
        for (int k = 0; k < 60; ++k) {
            float xv = xr[k];
            const float* wr = wk + k * NOUT;
#pragma unroll
            for (int j = 0; j < 13; ++j) acc[j] = fmaf(xv, wr[j], acc[j]);
        }

        // combine k-halves through the u-tile (double-buffered)
        float* ur = &us[cur][lane * NOUT + j0];
        if (kh == 0) {
            for (int j = 0; j < jcnt; ++j) ur[j] = acc[j];
        }
        __syncthreads();                       // B1: kh0 writes visible
        if (kh == 1) {
            for (int j = 0; j < jcnt; ++j) ur[j] += acc[j];
        }
        if (more) {                            // stage next tile into xs[nxt]
#pragma unroll
            for (int i = 0; i < 8; ++i) {
                int f = t + 256 * i;
                if (f < NF4) {
                    int r = f / 30, q = f - 30 * r;
                    float* d = &xs[nxt][r * XS + 4 * q];
                    d[0] = L[i].x; d[1] = L[i].y; d[2] = L[i].z; d[3] = L[i].w;
                }
            }
        }
        __syncthreads();                       // B2: u-tile complete, next staged

        // coalesced float4 store of the finished u-tile
        const float4* s4 = (const float4*)&us[cur][0];
        float4* d4 = (float4*)(u + (rowsBase + (long)tile * TROWS) * NOUT);
#pragma unroll
        for (int i = 0; i < 2; ++i) {
            int f = t + 256 * i;
            if (f < TROWS * NOUT / 4) d4[f] = s4[f];
        }
    }
}

__global__ __launch_bounds__(256) void route_kernel(
    const float* __restrict__ u,   // [batch*512, 25]
    float* __restrict__ out)       // [batch, 25]
{
    __shared__ __align__(16) float usm[SEQ * NOUT];  // 51,200 B
    __shared__ float red[4][NOUT];

    const int t    = threadIdx.x;
    const int lane = t & 63;
    const int wv   = t >> 6;

    // coalesced stage of this batch element's u_hat chunk
    const float4* src = (const float4*)(u + (size_t)blockIdx.x * SEQ * NOUT);
    float4* d4 = (float4*)usm;
#pragma unroll
    for (int i = 0; i < 13; ++i) {
        int f = t + 256 * i;
        if (f < SEQ * NOUT / 4) d4[f] = src[f];
    }
    __syncthreads();

    // rows t and t+256 into registers (stride 25 odd -> conflict-free)
    float uh[2][NOUT];
#pragma unroll
    for (int r = 0; r < 2; ++r) {
        const float* rr = &usm[(t + 256 * r) * NOUT];
#pragma unroll
        for (int j = 0; j < NOUT; ++j) uh[r][j] = rr[j];
    }

    float bb[2][NCAP];
#pragma unroll
    for (int r = 0; r < 2; ++r)
#pragma unroll
        for (int c = 0; c < NCAP; ++c) bb[r][c] = 0.f;

    float o[NOUT];

    for (int it = 0; it < ROUTINGS; ++it) {
        float p[NOUT];
#pragma unroll
        for (int j = 0; j < NOUT; ++j) p[j] = 0.f;

#pragma unroll
        for (int r = 0; r < 2; ++r) {
            float m = bb[r][0];
#pragma unroll
            for (int c = 1; c < NCAP; ++c) m = fmaxf(m, bb[r][c]);
            float e[NCAP]; float se = 0.f;
#pragma unroll
            for (int c = 0; c < NCAP; ++c) { e[c] = __expf(bb[r][c] - m); se += e[c]; }
            float inv = 1.f / se;
#pragma unroll
            for (int c = 0; c < NCAP; ++c) {
                float cc = e[c] * inv;
#pragma unroll
                for (int k = 0; k < DCAP; ++k)
                    p[c*DCAP + k] = fmaf(cc, uh[r][c*DCAP + k], p[c*DCAP + k]);
            }
        }

        // block reduction: 64-lane butterfly, then 4 waves via LDS
#pragma unroll
        for (int d = 1; d < 64; d <<= 1)
#pragma unroll
            for (int j = 0; j < NOUT; ++j) p[j] += __shfl_xor(p[j], d, 64);

        if (lane == 0) {
#pragma unroll
            for (int j = 0; j < NOUT; ++j) red[wv][j] = p[j];
        }
        __syncthreads();
        float s[NOUT];
#pragma unroll
        for (int j = 0; j < NOUT; ++j)
            s[j] = red[0][j] + red[1][j] + red[2][j] + red[3][j];
        __syncthreads();

#pragma unroll
        for (int c = 0; c < NCAP; ++c) {
            float ss = 0.f;
#pragma unroll
            for (int k = 0; k < DCAP; ++k)
                ss = fmaf(s[c*DCAP + k], s[c*DCAP + k], ss);
            float sc = rsqrtf(ss + 1e-7f);
#pragma unroll
            for (int k = 0; k < DCAP; ++k) o[c*DCAP + k] = s[c*DCAP + k] * sc;
        }

        if (it < ROUTINGS - 1) {
#pragma unroll
            for (int r = 0; r < 2; ++r)
#pragma unroll
                for (int c = 0; c < NCAP; ++c) {
                    float d0 = 0.f;
#pragma unroll
                    for (int k = 0; k < DCAP; ++k)
                        d0 = fmaf(o[c*DCAP + k], uh[r][c*DCAP + k], d0);
                    bb[r][c] = d0;
                }
        }
    }

    if (t < NOUT) out[(size_t)blockIdx.x * NOUT + t] = o[t];
}

extern "C" void kernel_launch(void* const* d_in, const int* in_sizes, int n_in,
                              void* d_out, int out_size, void* d_ws, size_t ws_size,
                              hipStream_t stream) {
    const float* x = (const float*)d_in[0];
    const float* W = (const float*)d_in[1];
    float* out     = (float*)d_out;
    float* u       = (float*)d_ws;                 // needs 524288*25*4 = 52.4 MB

    const int nrows = in_sizes[0] / DIN;           // 524288
    const int batch = nrows / SEQ;                 // 1024

    gemm_kernel <<<dim3(nrows / (TILES * TROWS)), dim3(256), 0, stream>>>(x, W, u);
    route_kernel<<<dim3(batch),                   dim3(256), 0, stream>>>(u, out);
}